// Round 6
// baseline (941.820 us; speedup 1.0000x reference)
//
#include <hip/hip_runtime.h>
#include <stdint.h>

// Problem constants (fixed by the reference setup_inputs):
#define M_DIM 4096
#define N_DIM 8192   // O
#define K_DIM 8192   // I
#define NB    256    // K/32 Q4_0 blocks per row

#define BM 256
#define BN 256
#define BK 64

typedef __attribute__((ext_vector_type(8)))  __bf16 bf16x8;
typedef __attribute__((ext_vector_type(16))) float  floatx16;
typedef __attribute__((ext_vector_type(4)))  unsigned short ushort4v;
typedef __attribute__((ext_vector_type(8)))  unsigned short ushort8;

__device__ __forceinline__ unsigned short f32_to_bf16_rne(float f) {
    union { float f; unsigned int u; } v; v.f = f;
    unsigned int u = v.u;
    u += 0x7FFFu + ((u >> 16) & 1u);
    return (unsigned short)(u >> 16);
}

// ---- fused prep: dequant W (even blocks) + convert x (odd blocks) ----------
// (round-4 version, unchanged — prep is at/near its BW floor; non-GEMM time
// is insensitive to prep implementation across rounds 0-4.)
__global__ __launch_bounds__(256) void prep(const int* __restrict__ qw,
                                            const float* __restrict__ sc,
                                            unsigned short* __restrict__ w,
                                            const float* __restrict__ x,
                                            unsigned short* __restrict__ xb) {
    const int bid = blockIdx.x;
    if (bid & 1) {
        size_t idx = ((size_t)(bid >> 1) * 256 + threadIdx.x) * 4;
        float4 f = *(const float4*)(x + idx);
        ushort4v o;
        o[0] = f32_to_bf16_rne(f.x); o[1] = f32_to_bf16_rne(f.y);
        o[2] = f32_to_bf16_rne(f.z); o[3] = f32_to_bf16_rne(f.w);
        *(ushort4v*)(xb + idx) = o;
    } else {
        const int tid = (bid >> 1) * 256 + threadIdx.x;   // 0 .. O*NB*4-1
        const int blk = tid >> 2;
        const int q   = tid & 3;
        const int4* src = (const int4*)qw + (size_t)blk * 4 + (q & 1) * 2;
        int4 v0 = src[0];
        int4 v1 = src[1];
        const float scale = sc[blk];
        const int sh = (q >> 1) * 4;   // 0 = lo nibble, 4 = hi nibble
        int by[8] = { v0.x, v0.y, v0.z, v0.w, v1.x, v1.y, v1.z, v1.w };
        ushort8 o;
#pragma unroll
        for (int j = 0; j < 8; ++j)
            o[j] = f32_to_bf16_rne((float)(((by[j] >> sh) & 0xF) - 8) * scale);
        *(ushort8*)(w + (size_t)blk * 32 + q * 8) = o;
    }
}

// =====================================================================
// GEMM: C[M,N] = A[M,K] * B[N,K]^T + bias  — 256x256 tile, FREE-RUN schedule
// 8 waves (2M x 4N), wave tile 128x64 = 4x2 frags of 32x32, BK=64.
// LDS: 2 tile buffers, 128 KiB.
//
// Round-5/6 theory: the 8-phase barrier lockstep forced [all-read | all-MFMA]
// serialization (LDS 2304 cyc + matrix 2066 cyc per tile per CU -> 47% util,
// matching measured 48%). Free-run: ONE barrier per K-tile; stage next tile
// into the OTHER buffer first (full-tile HBM lead -> vmcnt(0) at tile end is
// ~free), then 24 frag reads + 32 MFMAs with no pins — compiler emits counted
// lgkmcnt per consumer; waves drift -> cross-wave LDS/matrix overlap.
// setprio(1) around MFMA block arbitrates drifted waves (T5 mechanism).
//
// Race ledger:
//  * stage(t+1 -> buf^1) ... vmcnt(0)+BAR ... reads(t+1, buf^1): landed and
//    published. OK
//  * reads(t, buf bb) all retire before their MFMA consumers (compiler
//    lgkmcnt), hence before the end BAR; bb overwritten only in tile t+1
//    after that BAR. OK
//  * One barrier per tile serves both directions.
// Swizzle: LDS slot s holds global 16B-slot s ^ f(row), f=(row^(row>>3))&7;
// linear LDS dest + pre-swizzled global source (rule #21). Unchanged.
// =====================================================================
__device__ __forceinline__ void load_lds16(const unsigned short* g, unsigned short* l) {
    __builtin_amdgcn_global_load_lds(
        (const __attribute__((address_space(1))) unsigned int*)(g),
        (__attribute__((address_space(3))) unsigned int*)(l),
        16, 0, 0);
}

__device__ __forceinline__ floatx16 mfma_op(bf16x8 a, bf16x8 b, floatx16 c) {
    return __builtin_amdgcn_mfma_f32_32x32x16_bf16(a, b, c, 0, 0, 0);
}

// slot select on read: global slot (kk*2+q5), LDS slot = global ^ f(row)
#define SL(kk, F) (((((kk) * 2) + q5) ^ (F)) * 8)

// one half-tile = 128 rows of one array = 2 global_load_lds per thread
#define STAGE_A(b, h, kb) do { \
    load_lds16(gA + (size_t)((h) * 128 +  0) * K_DIM + (kb) * BK, &lsA[b][((h) * 128 +  0 + wave * 8) * BK]); \
    load_lds16(gA + (size_t)((h) * 128 + 64) * K_DIM + (kb) * BK, &lsA[b][((h) * 128 + 64 + wave * 8) * BK]); \
} while (0)
#define STAGE_B(b, h, kb) do { \
    load_lds16(gB + (size_t)((h) * 128 +  0) * K_DIM + (kb) * BK, &lsB[b][((h) * 128 +  0 + wave * 8) * BK]); \
    load_lds16(gB + (size_t)((h) * 128 + 64) * K_DIM + (kb) * BK, &lsB[b][((h) * 128 + 64 + wave * 8) * BK]); \
} while (0)
#define STAGE_ALL(dst, kb) do { \
    STAGE_A(dst, 0, kb); STAGE_A(dst, 1, kb); \
    STAGE_B(dst, 0, kb); STAGE_B(dst, 1, kb); \
} while (0)

#define CL(ai, jj, av, bv) \
    _Pragma("unroll") for (int kk = 0; kk < 4; ++kk) \
        acc[ai][jj] = mfma_op(av[kk], bv[kk], acc[ai][jj]);

#define PRIO1   __builtin_amdgcn_s_setprio(1)
#define PRIO0   __builtin_amdgcn_s_setprio(0)
#define BAR     __builtin_amdgcn_s_barrier()

// One K-tile, free-run. bb = compile-time buffer literal. STAGES prefetches
// tile t+1 into buf bb^1 (or empty for the last tile). TAIL = vmcnt+BAR.
#define TILE_FREE(bb, STAGES, TAILOP) do { \
    STAGES; \
    _Pragma("unroll") for (int kk = 0; kk < 4; ++kk) { \
        b0[kk]    = *(const bf16x8*)(&lsB[bb][aB0 + SL(kk, F0)]); \
        b1[kk]    = *(const bf16x8*)(&lsB[bb][aB1 + SL(kk, F1)]); \
        aL[0][kk] = *(const bf16x8*)(&lsA[bb][aA0 + SL(kk, F0)]); \
        aL[1][kk] = *(const bf16x8*)(&lsA[bb][aA1 + SL(kk, F1)]); \
        aH[0][kk] = *(const bf16x8*)(&lsA[bb][aA2 + SL(kk, F0)]); \
        aH[1][kk] = *(const bf16x8*)(&lsA[bb][aA3 + SL(kk, F1)]); \
    } \
    PRIO1; \
    CL(0, 0, aL[0], b0); CL(1, 0, aL[1], b0); \
    CL(0, 1, aL[0], b1); CL(1, 1, aL[1], b1); \
    CL(2, 0, aH[0], b0); CL(3, 0, aH[1], b0); \
    CL(2, 1, aH[0], b1); CL(3, 1, aH[1], b1); \
    PRIO0; \
    TAILOP; \
} while (0)

#define TILE_TAIL do { \
    asm volatile("s_waitcnt vmcnt(0)" ::: "memory"); \
    BAR; \
} while (0)

__global__ __launch_bounds__(512, 2) void gemm_bt(const unsigned short* __restrict__ A,
                                                  const unsigned short* __restrict__ B,
                                                  const float* __restrict__ bias,
                                                  float* __restrict__ C) {
    __shared__ unsigned short lsA[2][BM * BK];   // 2 x 32 KiB
    __shared__ unsigned short lsB[2][BN * BK];   // 2 x 32 KiB

    const int tid  = threadIdx.x;
    const int wave = tid >> 6;
    const int lane = tid & 63;
    const int wm = wave >> 2;   // 0..1 : 128-row stripe of M
    const int wn = wave & 3;    // 0..3 : 64-col stripe of N

    // XCD-bijective swizzle (512 wgs % 8 == 0): each XCD gets 64 consecutive
    // wgs = 2 full tile-rows -> concurrent blocks share one 4 MiB A-panel in L2.
    const int bid = blockIdx.x;
    const int wg  = (bid & 7) * 64 + (bid >> 3);
    const int m0 = (wg >> 5) * BM;   // 16 tile-rows
    const int n0 = (wg & 31) * BN;   // 32 tile-cols

    // ---- staging addresses ----
    // LDS row r = h*128 + t*64 + wave*8 + lrow, slot = l7s (linear dest).
    // f(r) = (r ^ (r>>3)) & 7 = lrow ^ wave  (h,t contribute multiples of 8).
    const int lrow = lane >> 3;
    const int l7s  = lane & 7;
    const int csrc = ((l7s ^ lrow ^ wave) & 7) * 8;   // pre-swizzled source column
    const unsigned short* gA = A + (size_t)(m0 + wave * 8 + lrow) * K_DIM + csrc;
    const unsigned short* gB = B + (size_t)(n0 + wave * 8 + lrow) * K_DIM + csrc;

    // ---- fragment read addresses (32x32x16: A[m=lane&31][k=(lane>>5)*8+j]) ----
    const int q5  = lane >> 5;
    const int r31 = lane & 31;
    const int l7  = lane & 7;
    const int rh  = r31 >> 3;
    const int aA0 = (wm * 128 +  0 + r31) * BK;
    const int aA1 = (wm * 128 + 32 + r31) * BK;
    const int aA2 = (wm * 128 + 64 + r31) * BK;
    const int aA3 = (wm * 128 + 96 + r31) * BK;
    const int aB0 = (wn * 64  +  0 + r31) * BK;
    const int aB1 = (wn * 64  + 32 + r31) * BK;
    const int F0  = l7 ^ (rh & 7);         // f(row) for frag row-blocks 0,2
    const int F1  = l7 ^ ((4 + rh) & 7);   // row-blocks 1,3

    floatx16 acc[4][2] = {};
    bf16x8 aL[2][4], aH[2][4], b0[4], b1[4];

    // ---- prologue: stage tile0 -> buf0, drain, publish ----
    STAGE_ALL(0, 0);
    asm volatile("s_waitcnt vmcnt(0)" ::: "memory");
    BAR;

    // ---- main loop: 63 iterations x 2 K-tiles; tiles 126,127 peeled ----
    for (int i = 0; i < 63; ++i) {
        const int t0 = 2 * i;
        TILE_FREE(0, STAGE_ALL(1, t0 + 1), TILE_TAIL);
        TILE_FREE(1, STAGE_ALL(0, t0 + 2), TILE_TAIL);
    }
    TILE_FREE(0, STAGE_ALL(1, 127), TILE_TAIL);
    TILE_FREE(1, (void)0, (void)0);

    // ---- epilogue. 32x32 C/D: col = lane&31, row = (r&3) + 8*(r>>2) + 4*q5 ----
#pragma unroll
    for (int fj = 0; fj < 2; ++fj) {
        const int col = n0 + wn * 64 + fj * 32 + r31;
        const float bv = bias[col];
#pragma unroll
        for (int fi = 0; fi < 4; ++fi) {
            const int rowbase = m0 + wm * 128 + fi * 32 + q5 * 4;
            const floatx16 av = acc[fi][fj];
#pragma unroll
            for (int r = 0; r < 16; ++r) {
                const int row = rowbase + (r & 3) + 8 * (r >> 2);
                C[(size_t)row * N_DIM + col] = av[r] + bv;
            }
        }
    }
}

extern "C" void kernel_launch(void* const* d_in, const int* in_sizes, int n_in,
                              void* d_out, int out_size, void* d_ws, size_t ws_size,
                              hipStream_t stream) {
    (void)in_sizes; (void)n_in; (void)out_size; (void)ws_size;
    const float* x    = (const float*)d_in[0];
    const int*   qw   = (const int*)d_in[1];
    const float* sc   = (const float*)d_in[2];
    const float* bias = (const float*)d_in[3];
    float* out = (float*)d_out;

    unsigned short* Wb = (unsigned short*)d_ws;                                      // 128 MiB
    unsigned short* Xb = (unsigned short*)((char*)d_ws + (size_t)N_DIM * K_DIM * 2); // +64 MiB

    // fused prep: 32768 dequant blocks (even bids) + 32768 convert blocks (odd)
    prep<<<dim3(65536), dim3(256), 0, stream>>>(qw, sc, Wb, x, Xb);
    gemm_bt<<<dim3((M_DIM / BM) * (N_DIM / BN)), dim3(512), 0, stream>>>(Xb, Wb, bias, out);
}